// Round 2
// baseline (284.984 us; speedup 1.0000x reference)
//
#include <hip/hip_runtime.h>
#include <hip/hip_bf16.h>

typedef __bf16 v4bf __attribute__((ext_vector_type(4)));
typedef __bf16 v8bf __attribute__((ext_vector_type(8)));
typedef float  v16f __attribute__((ext_vector_type(16)));
typedef float  f4v  __attribute__((ext_vector_type(4)));
typedef unsigned int u4v __attribute__((ext_vector_type(4)));

#define LOG2E 1.44269504088896340736f

// round-to-nearest-even float -> bf16 bits
__device__ __forceinline__ unsigned short f2bf(float f) {
    union { float f; unsigned int u; } a; a.f = f;
    unsigned int r = a.u + 0x7FFFu + ((a.u >> 16) & 1u);
    return (unsigned short)(r >> 16);
}

__device__ __forceinline__ void unpack8v(u4v w, float* f) {
    #pragma unroll
    for (int i = 0; i < 4; ++i) {
        f[2 * i]     = __uint_as_float(w[i] << 16);
        f[2 * i + 1] = __uint_as_float(w[i] & 0xFFFF0000u);
    }
}

// ---------------- Phase 0: pack W^T bf16 + zero deg (fused) ----------------
// k & q weights pre-scaled by log2(e); k additionally NEGATED so the
// gather kernel reads nk = -k' directly (sigmoid = rcp(1 + 2^(nk - q'))).
__global__ __launch_bounds__(256) void prep_w_zero(
    const float* __restrict__ Wk, const float* __restrict__ Wq,
    const float* __restrict__ Wv, const float* __restrict__ Ws,
    unsigned short* __restrict__ Wt, int* __restrict__ deg, int N)
{
    int i = blockIdx.x * 256 + threadIdx.x;      // 512 blocks -> 131072 threads
    if (i < 65536) {
        int m = i >> 14;
        int r = i & 16383;
        int n = r >> 7, k = r & 127;
        const float* W = (m == 0) ? Wk : (m == 1) ? Wq : (m == 2) ? Wv : Ws;
        float scale = (m == 0) ? -LOG2E : (m == 1) ? LOG2E : 1.0f;
        Wt[i] = f2bf(W[k * 128 + n] * scale);
    }
    if (i < N) deg[i] = 0;
}

// ---------------- Phase 1: fused MFMA GEMM, x read once ----------------
// 1024 threads = 16 waves = 16 (mat, col-tile) combos. B-frags register-
// resident; grid-stride over 32-row x-tiles staged in LDS (bf16, stride
// 132 -> 2-way bank alias = free); next tile prefetched into registers.
// q and v written INTERLEAVED: qv[node] = [q' 128 | v 128] (bf16).
// kws holds -k' (negated in weight prep).
__global__ __launch_bounds__(1024, 4) void gemm_fused(
    const float* __restrict__ x, int N,
    const unsigned short* __restrict__ Wt,
    const float* __restrict__ bk, const float* __restrict__ bq,
    const float* __restrict__ bv, const float* __restrict__ bs,
    unsigned short* __restrict__ kws, unsigned short* __restrict__ qv,
    float* __restrict__ out)
{
    __shared__ __align__(16) unsigned short xs[32 * 132];
    const int t   = threadIdx.x;
    const int wid = t >> 6;          // 0..15
    const int m   = wid >> 2;        // matrix
    const int ct  = wid & 3;         // col tile
    const int l   = t & 63;
    const int col = ct * 32 + (l & 31);
    const int kb  = (l >> 5) * 8;

    // B fragments, loaded once (L2-resident after first blocks)
    v8bf b[8];
    {
        const unsigned short* wp = Wt + m * 16384 + col * 128 + kb;
        #pragma unroll
        for (int c = 0; c < 8; ++c) b[c] = *(const v8bf*)(wp + c * 16);
    }
    const float* bvec = (m == 0) ? bk : (m == 1) ? bq : (m == 2) ? bv : bs;
    const float bcol = bvec[col] * ((m == 0) ? -LOG2E : (m == 1) ? LOG2E : 1.0f);
    unsigned short* dst; int dstride;
    if (m == 0)      { dst = kws;      dstride = 128; }
    else if (m == 1) { dst = qv;       dstride = 256; }
    else             { dst = qv + 128; dstride = 256; }   // m==2 (v half)

    // staging: thread owns one float4 of the 32x128 tile
    const int srow = t >> 5;         // 0..31
    const int sk4  = (t & 31) << 2;  // 0..124
    const int rowb = 4 * (l >> 5);

    const int ntiles = (N + 31) >> 5;
    int tile = blockIdx.x;
    if (tile >= ntiles) return;

    float4 stg = make_float4(0.f, 0.f, 0.f, 0.f);
    {
        int gr = tile * 32 + srow;
        if (gr < N) stg = *(const float4*)(x + (size_t)gr * 128 + sk4);
    }

    const unsigned short* ap = xs + (l & 31) * 132 + kb;

    while (true) {
        // write staged tile to LDS as bf16
        ushort4 pk;
        pk.x = f2bf(stg.x); pk.y = f2bf(stg.y);
        pk.z = f2bf(stg.z); pk.w = f2bf(stg.w);
        *(ushort4*)(xs + srow * 132 + sk4) = pk;
        __syncthreads();

        // prefetch next tile while computing this one
        int next = tile + gridDim.x;
        if (next < ntiles) {
            int gr = next * 32 + srow;
            stg = (gr < N) ? *(const float4*)(x + (size_t)gr * 128 + sk4)
                           : make_float4(0.f, 0.f, 0.f, 0.f);
        }

        // fused LDS-read + MFMA chain (a-frags transient: low VGPR)
        v16f acc = {};
        #pragma unroll
        for (int c = 0; c < 8; ++c) {
            v4bf a0 = *(const v4bf*)(ap + c * 16);
            v4bf a1 = *(const v4bf*)(ap + c * 16 + 4);
            v8bf a = __builtin_shufflevector(a0, a1, 0, 1, 2, 3, 4, 5, 6, 7);
            acc = __builtin_amdgcn_mfma_f32_32x32x16_bf16(a, b[c], acc, 0, 0, 0);
        }

        // C/D: col = lane&31, row = (reg&3) + 8*(reg>>2) + 4*(lane>>5)
        const int r0 = tile * 32 + rowb;
        if (m == 3) {
            #pragma unroll
            for (int reg = 0; reg < 16; ++reg) {
                int row = r0 + (reg & 3) + 8 * (reg >> 2);
                if (row < N) out[(size_t)row * 128 + col] = acc[reg] + bcol;
            }
        } else {
            #pragma unroll
            for (int reg = 0; reg < 16; ++reg) {
                int row = r0 + (reg & 3) + 8 * (reg >> 2);
                if (row < N) dst[(size_t)row * dstride + col] = f2bf(acc[reg] + bcol);
            }
        }

        tile = next;
        if (tile >= ntiles) break;
        __syncthreads();   // all A-frag reads done before next staging write
    }
}

// ---------------- Phase 2: device-built CSR (single-atomic counting sort) ----------------

__global__ __launch_bounds__(256) void count_pos(
    const int* __restrict__ ei, int E, int* __restrict__ deg,
    int* __restrict__ pos)
{
    int e = blockIdx.x * 256 + threadIdx.x;
    if (e >= E) return;
    pos[e] = atomicAdd(&deg[ei[E + e]], 1);   // dst
}

__global__ __launch_bounds__(256) void scan_chunks(
    const int* __restrict__ deg, int N, int* __restrict__ rowStart,
    int* __restrict__ chunkTot)
{
    __shared__ int sums[256];
    const int t = threadIdx.x;
    const int base = blockIdx.x * 1024 + t * 4;
    int d0 = 0, d1 = 0, d2 = 0, d3 = 0;
    if (base + 3 < N) {
        int4 dd = *(const int4*)(deg + base);
        d0 = dd.x; d1 = dd.y; d2 = dd.z; d3 = dd.w;
    } else {
        if (base + 0 < N) d0 = deg[base + 0];
        if (base + 1 < N) d1 = deg[base + 1];
        if (base + 2 < N) d2 = deg[base + 2];
        if (base + 3 < N) d3 = deg[base + 3];
    }
    int tot = d0 + d1 + d2 + d3;
    sums[t] = tot;
    __syncthreads();
    #pragma unroll
    for (int off = 1; off < 256; off <<= 1) {
        int v = (t >= off) ? sums[t - off] : 0;
        __syncthreads();
        sums[t] += v;
        __syncthreads();
    }
    int excl = sums[t] - tot;
    if (base + 0 < N) rowStart[base + 0] = excl;
    if (base + 1 < N) rowStart[base + 1] = excl + d0;
    if (base + 2 < N) rowStart[base + 2] = excl + d0 + d1;
    if (base + 3 < N) rowStart[base + 3] = excl + d0 + d1 + d2;
    if (t == 255) chunkTot[blockIdx.x] = sums[255];
}

// add chunk offsets; each block re-scans the (<=128) chunk totals in LDS
__global__ __launch_bounds__(256) void add_offsets(
    int* __restrict__ rowStart, const int* __restrict__ chunkTot,
    int N, int nChunks)
{
    __shared__ int s[128];
    const int t = threadIdx.x;
    if (t < 128) s[t] = (t < nChunks) ? chunkTot[t] : 0;
    __syncthreads();
    #pragma unroll
    for (int off = 1; off < 128; off <<= 1) {
        int u = 0;
        if (t < 128 && t >= off) u = s[t - off];
        __syncthreads();
        if (t < 128) s[t] += u;
        __syncthreads();
    }
    const int coff = (blockIdx.x == 0) ? 0 : s[blockIdx.x - 1];
    const int base = blockIdx.x * 1024 + t * 4;
    if (base + 3 < N) {
        int4 r = *(const int4*)(rowStart + base);
        r.x += coff; r.y += coff; r.z += coff; r.w += coff;
        *(int4*)(rowStart + base) = r;
    } else {
        #pragma unroll
        for (int j = 0; j < 4; ++j) {
            if (base + j < N) rowStart[base + j] += coff;
        }
    }
}

__global__ __launch_bounds__(256) void fill_csr(
    const int* __restrict__ ei, int E,
    const int* __restrict__ rowStart, const int* __restrict__ pos,
    int* __restrict__ elist)
{
    int e = blockIdx.x * 256 + threadIdx.x;
    if (e >= E) return;
    int s = ei[e];
    int d = ei[E + e];
    elist[rowStart[d] + pos[e]] = s;   // atomic-free scatter
}

// ---------------- Phase 3: owner-computes aggregation (no atomics) ----------------
// 4 nodes/wave (16 lanes each), lane owns 8 feats; q|v interleaved rows.
// Chunk-4 exact-trip loop with 2-deep ping-pong pipeline: next chunk's 8
// gathers issued before current chunk's math, no serial remainder, only
// ~1.16x slot inflation (vs 1.5x for chunk-8). Streaming traffic (out RMW,
// kws, elist) uses non-temporal hints to preserve cache for the qv table.
__global__ __launch_bounds__(256, 4) void gather_agg(
    const int* __restrict__ rowStart, const int* __restrict__ deg,
    const int* __restrict__ elist,
    const unsigned short* __restrict__ kws,
    const unsigned short* __restrict__ qv,
    float* __restrict__ out, int N)
{
    int gid = blockIdx.x * 256 + threadIdx.x;
    int node = gid >> 4;
    if (node >= N) return;
    int fo = (gid & 15) << 3;   // 8 feats per lane

    // issue long-latency independent loads first
    float* orow = out + (size_t)node * 128 + fo;
    f4v o0 = __builtin_nontemporal_load((const f4v*)orow);
    f4v o1 = __builtin_nontemporal_load((const f4v*)(orow + 4));
    u4v kraw = __builtin_nontemporal_load((const u4v*)(kws + (size_t)node * 128 + fo));
    const int p0 = rowStart[node];
    const int dg = deg[node];

    float nkf[8];
    unpack8v(kraw, nkf);   // holds -k' already
    float acc[8] = {};

    const unsigned short* qvb = qv + fo;
    const int e = p0 + dg;

    if (dg > 0) {
        u4v qA[4], vA[4], qB[4], vB[4];

#define LOADC(b, qr, vr)                                                     \
        {                                                                    \
            _Pragma("unroll")                                                \
            for (int s = 0; s < 4; ++s) {                                    \
                int pp = (b) + s;                                            \
                int ix = __builtin_nontemporal_load(elist + (pp < e ? pp : e - 1)); \
                const unsigned short* r = qvb + (ix << 8);                   \
                qr[s] = *(const u4v*)(r);                                    \
                vr[s] = *(const u4v*)(r + 128);                              \
            }                                                                \
        }

#define COMP(b, qr, vr)                                                     \
        {                                                                   \
            _Pragma("unroll")                                               \
            for (int s = 0; s < 4; ++s) {                                   \
                u4v vv = vr[s];                                             \
                if ((b) + s >= e) { vv[0]=0u; vv[1]=0u; vv[2]=0u; vv[3]=0u; } \
                float qf[8], vf[8];                                         \
                unpack8v(qr[s], qf);                                        \
                unpack8v(vv, vf);                                           \
                _Pragma("unroll")                                           \
                for (int j = 0; j < 8; ++j) {                               \
                    float ex = __builtin_amdgcn_exp2f(nkf[j] - qf[j]);      \
                    acc[j] = fmaf(__builtin_amdgcn_rcpf(1.0f + ex), vf[j], acc[j]); \
                }                                                           \
            }                                                               \
        }

        int base = p0;
        LOADC(base, qA, vA);
        while (true) {
            int nb = base + 4;
            if (nb < e) {
                LOADC(nb, qB, vB);          // pipeline: issue next chunk's loads
                COMP(base, qA, vA);         // ...then compute current chunk
                base = nb;
                nb = base + 4;
                if (nb < e) {
                    LOADC(nb, qA, vA);
                    COMP(base, qB, vB);
                    base = nb;
                } else {
                    COMP(base, qB, vB);
                    break;
                }
            } else {
                COMP(base, qA, vA);
                break;
            }
        }
#undef LOADC
#undef COMP
    }

    o0[0] += acc[0]; o0[1] += acc[1]; o0[2] += acc[2]; o0[3] += acc[3];
    o1[0] += acc[4]; o1[1] += acc[5]; o1[2] += acc[6]; o1[3] += acc[7];
    __builtin_nontemporal_store(o0, (f4v*)orow);
    __builtin_nontemporal_store(o1, (f4v*)(orow + 4));
}

extern "C" void kernel_launch(void* const* d_in, const int* in_sizes, int n_in,
                              void* d_out, int out_size, void* d_ws, size_t ws_size,
                              hipStream_t stream) {
    const float* x    = (const float*)d_in[0];
    const int*   ei   = (const int*)d_in[1];
    const float* Wk   = (const float*)d_in[3];
    const float* bk   = (const float*)d_in[4];
    const float* Wq   = (const float*)d_in[5];
    const float* bq   = (const float*)d_in[6];
    const float* Wv   = (const float*)d_in[7];
    const float* bv   = (const float*)d_in[8];
    const float* Ws   = (const float*)d_in[9];
    const float* bias = (const float*)d_in[10];

    const int N = in_sizes[0] / 128;
    const int E = in_sizes[1] / 2;
    float* out = (float*)d_out;

    // workspace layout
    unsigned short* kws = (unsigned short*)d_ws;        // N*128 bf16 (-k', scaled)
    unsigned short* qv  = kws + (size_t)N * 128;        // N*256 bf16 (q'|v)
    int* deg      = (int*)(qv + (size_t)N * 256);
    int* rowStart = deg + N;
    int* chunkTot = rowStart + N;
    int* pos      = chunkTot + 128;                     // E ints (per-edge slot)
    int* elist    = pos + E;
    unsigned short* Wt = (unsigned short*)(elist + E);

    const int nChunks = (N + 1023) / 1024;

    prep_w_zero<<<512, 256, 0, stream>>>(Wk, Wq, Wv, Ws, Wt, deg, N);
    gemm_fused<<<1024, 1024, 0, stream>>>(
        x, N, Wt, bk, bq, bv, bias, kws, qv, out);

    count_pos<<<(E + 255) / 256, 256, 0, stream>>>(ei, E, deg, pos);
    scan_chunks<<<nChunks, 256, 0, stream>>>(deg, N, rowStart, chunkTot);
    add_offsets<<<nChunks, 256, 0, stream>>>(rowStart, chunkTot, N, nChunks);
    fill_csr<<<(E + 255) / 256, 256, 0, stream>>>(ei, E, rowStart, pos, elist);

    gather_agg<<<((size_t)N * 16 + 255) / 256, 256, 0, stream>>>(
        rowStart, deg, elist, kws, qv, out, N);
}